// Round 16
// baseline (213.631 us; speedup 1.0000x reference)
//
#include <hip/hip_runtime.h>
#include <hip/hip_bf16.h>
#include <math.h>

#define BN 4096   // batch per domain
#define DD 256    // feature dim
#define CC 31     // label classes
#define KP 352    // packed k per row: 256 feat + 32 augA + 32 augB + 32 label
#define AUGA 256
#define AUGB 288
#define LABK 320

typedef __attribute__((ext_vector_type(8))) short bf16x8;
typedef __attribute__((ext_vector_type(4))) float f32x4;

static __device__ inline unsigned short f2bf(float v) {
  __hip_bfloat16 h = __float2bfloat16(v);
  union { __hip_bfloat16 h; unsigned short u; } cv;
  cv.h = h;
  return cv.u;
}
static __device__ inline float bf2f(unsigned short u) {
  return __uint_as_float(((unsigned int)u) << 16);
}

// ---------------- workspace layout ----------------
// [0]        double loss_acc
// [1]        double sum_sq
// [2..257]   double colsum[256]
// [258..289] double labsumS[32]
// [290..321] double labsumT[32]      (ends at byte 2576)
// byte 2576: int counter1; byte 2580: int counter2
// byte 2624: float aScale[32], bScale[32], negc[8]
// byte 4096: unsigned short pack[8192][352]   (~5.8 MB)

// ---------------- fused stats + bw + scales (last-block pattern) -------------
// 256 blocks x 256 threads. After all blocks' atomics complete (barrier drains
// vmcnt incl. atomics; __threadfence before counter), the last block computes
// bw coefficients and label scales, reading sums via atomicAdd(p, 0.0).
__global__ void stats_kernel(const float* __restrict__ source,
                             const float* __restrict__ target,
                             const float* __restrict__ s_label,
                             const float* __restrict__ t_label,
                             double* __restrict__ colsum,
                             double* __restrict__ sumsq,
                             double* __restrict__ labsumS,
                             double* __restrict__ labsumT,
                             int* __restrict__ counter1,
                             float* __restrict__ negc,
                             float* __restrict__ aScale,
                             float* __restrict__ bScale) {
  const int d = threadIdx.x;
  const int r0 = blockIdx.x * 32;
  float cs = 0.f, sq = 0.f;
  for (int r = r0; r < r0 + 32; ++r) {
    const float v = (r < BN) ? source[(size_t)r * DD + d]
                             : target[(size_t)(r - BN) * DD + d];
    cs += v;
    sq += v * v;
  }
  atomicAdd(&colsum[d], (double)cs);
  __shared__ float red[256];
  red[d] = sq;
  __syncthreads();
  for (int s = 128; s; s >>= 1) {
    if (d < s) red[d] += red[d + s];
    __syncthreads();
  }
  if (d == 0) atomicAdd(sumsq, (double)red[0]);

  if (d < CC) {
    const bool isS = (blockIdx.x < 128);
    const int lr0 = (isS ? blockIdx.x : blockIdx.x - 128) * 32;
    const float* lab = isS ? s_label : t_label;
    float ls = 0.f;
    for (int r = lr0; r < lr0 + 32; ++r) ls += lab[(size_t)r * CC + d];
    atomicAdd(isS ? &labsumS[d] : &labsumT[d], (double)ls);
  }

  // ---- last-block finalization ----
  __shared__ int amLast;
  __syncthreads();  // barrier drains this block's outstanding atomics
  if (d == 0) {
    __threadfence();
    amLast = (atomicAdd(counter1, 1) == 255) ? 1 : 0;
  }
  __syncthreads();
  if (!amLast) return;

  __shared__ double red2[256];
  double cv = atomicAdd(&colsum[d], 0.0);  // coherent read
  red2[d] = cv * cv;
  __syncthreads();
  for (int s = 128; s; s >>= 1) {
    if (d < s) red2[d] += red2[d + s];
    __syncthreads();
  }
  if (d == 0) {
    double ss = atomicAdd(sumsq, 0.0);
    double suml2 = 2.0 * 8192.0 * ss - 2.0 * red2[0];
    double bw = suml2 / (8192.0 * 8192.0 - 8192.0);
    bw = bw / 4.0;  // KERNEL_MUL^(KERNEL_NUM//2)
    for (int k = 0; k < 5; ++k)
      negc[k] = (float)(-1.0 / (bw * (double)(1 << k)));
  }
  if (d < 32) {
    double s_sum = (d < CC) ? atomicAdd(&labsumS[d], 0.0) : 0.0;
    double t_sum = (d < CC) ? atomicAdd(&labsumT[d], 0.0) : 0.0;
    bool valid = (d < CC) && (s_sum != 0.0) && (t_sum != 0.0);
    aScale[d] = valid ? (float)(1.0 / s_sum) : 0.f;
    bScale[d] = valid ? (float)(1.0 / t_sum) : 0.f;
  }
}

// ---------------- pack kernel: fp32 -> bf16 rows with aug + labels ----------------
__global__ void pack_kernel(const float* __restrict__ source,
                            const float* __restrict__ target,
                            const float* __restrict__ s_label,
                            const float* __restrict__ t_label,
                            const float* __restrict__ aScale,
                            const float* __restrict__ bScale,
                            unsigned short* __restrict__ pack) {
  const int vr = blockIdx.x * 4 + (threadIdx.x >> 6);  // 0..8191
  const int l = threadIdx.x & 63;
  const bool isS = (vr < BN);
  const float* xp = isS ? (source + (size_t)vr * DD)
                        : (target + (size_t)(vr - BN) * DD);
  float4 v = ((const float4*)xp)[l];
  unsigned short ub[4] = {f2bf(v.x), f2bf(v.y), f2bf(v.z), f2bf(v.w)};
  float f[4];
#pragma unroll
  for (int e = 0; e < 4; ++e) f[e] = bf2f(ub[e]);
  float sq = f[0] * f[0] + f[1] * f[1] + f[2] * f[2] + f[3] * f[3];
#pragma unroll
  for (int off = 32; off; off >>= 1) sq += __shfl_xor(sq, off);

  const size_t rb = (size_t)vr * KP;
  *(short4*)&pack[rb + l * 4] =
      make_short4((short)ub[0], (short)ub[1], (short)ub[2], (short)ub[3]);

  if (l < 8) {
    const unsigned short one = f2bf(1.0f);
    const float hs = -0.5f * sq;
    const unsigned short hh = f2bf(hs);
    const unsigned short lo = f2bf(hs - bf2f(hh));
    const int c0 = l * 4;
    unsigned short a_aug[4], b_aug[4], labv[4];
#pragma unroll
    for (int e = 0; e < 4; ++e) {
      const int c = c0 + e;
      a_aug[e] = (c == 0) ? hh : (c == 1) ? lo : (c <= 3) ? one : (unsigned short)0;
      b_aug[e] = (c <= 1) ? one : (c == 2) ? hh : (c == 3) ? lo : (unsigned short)0;
      float lv = 0.f;
      if (c < CC) {
        lv = isS ? s_label[(size_t)vr * CC + c] * aScale[c]
                 : t_label[(size_t)(vr - BN) * CC + c] * bScale[c];
      }
      labv[e] = f2bf(lv);
    }
    *(short4*)&pack[rb + AUGA + c0] = make_short4(
        (short)a_aug[0], (short)a_aug[1], (short)a_aug[2], (short)a_aug[3]);
    *(short4*)&pack[rb + AUGB + c0] = make_short4(
        (short)b_aug[0], (short)b_aug[1], (short)b_aug[2], (short)b_aug[3]);
    *(short4*)&pack[rb + LABK + c0] = make_short4(
        (short)labv[0], (short)labv[1], (short)labv[2], (short)labv[3]);
  }
}

// ---------------- main fused kernel (16x16x32 MFMA, symmetric upper-tri) -----
// Block (bi,bj), bi<=bj only (others exit; 2080 active of 4096).
// 4 dot streams from the SAME register operands (no extra loads):
//   SS=aS*bS  TT=aT*bT  ST1=aS*bT  ST2=aT*bS (transposed cross terms).
// Contribution = w * (wSS*Kss + wTT*Ktt - wST1*Kst1 - wST2*Kst2), w=2 off-diag
// (covers (bi,bj)+(bj,bi)), w=1 diagonal (ST1==ST2 there -> SS+TT-2ST exactly).
// Last block (counter2) converts the f64 accumulator to f32 out (finalize fused).
__global__ __launch_bounds__(256) void lmmd_main(
    const unsigned short* __restrict__ pack, const float* __restrict__ negc,
    double* __restrict__ accOut, int* __restrict__ counter2,
    float* __restrict__ out) {
  const int t = threadIdx.x;
  const int bi = blockIdx.x >> 6;
  const int bj = blockIdx.x & 63;

  if (bi > bj) {  // block-uniform exit; still participate in completion count
    if (t == 0) {
      __threadfence();
      if (atomicAdd(counter2, 1) == 4095) {
        double v = atomicAdd(accOut, 0.0);
        out[0] = (float)v;
      }
    }
    return;
  }

  __shared__ __align__(16) unsigned short bufB[2][128][32];  // 16 KB
  __shared__ double dred[256];

  const int lane = t & 63;
  const int wv = t >> 6;
  const int r15 = lane & 15;
  const int kb0 = (lane >> 4) * 8;

  const int rowSi = (bi * 64 + wv * 16 + r15) * KP;
  const int rowTi = rowSi + BN * KP;

  const int srow = t >> 1;        // 0..127 (0-63 S, 64-127 T)
  const int soff = (t & 1) * 16;  // short offset within row
  const int srowG = (srow < 64) ? (bj * 64 + srow) : (BN + bj * 64 + (srow - 64));
  const size_t sbase = (size_t)srowG * KP;

  constexpr int koAarr[10] = {0, 32, 64, 96, 128, 160, 192, 224, AUGA, LABK};
  constexpr int koBarr[10] = {0, 32, 64, 96, 128, 160, 192, 224, AUGB, LABK};

  f32x4 aSS[4], aTT[4], aST1[4], aST2[4], wSS[4], wTT[4], wST1[4], wST2[4];
#pragma unroll
  for (int n = 0; n < 4; ++n) {
    aSS[n] = {0.f, 0.f, 0.f, 0.f};
    aTT[n] = {0.f, 0.f, 0.f, 0.f};
    aST1[n] = {0.f, 0.f, 0.f, 0.f};
    aST2[n] = {0.f, 0.f, 0.f, 0.f};
    wSS[n] = {0.f, 0.f, 0.f, 0.f};
    wTT[n] = {0.f, 0.f, 0.f, 0.f};
    wST1[n] = {0.f, 0.f, 0.f, 0.f};
    wST2[n] = {0.f, 0.f, 0.f, 0.f};
  }

  // prologue: stage chunk 0 into buf 0
  {
    const float4 v0 = *(const float4*)&pack[sbase + koBarr[0] + soff];
    const float4 v1 = *(const float4*)&pack[sbase + koBarr[0] + soff + 8];
    *(float4*)&bufB[0][srow][soff] = v0;
    *(float4*)&bufB[0][srow][soff + 8] = v1;
  }

#pragma unroll
  for (int c = 0; c < 10; ++c) {
    __syncthreads();
    float4 s0, s1;
    if (c < 9) {
      s0 = *(const float4*)&pack[sbase + koBarr[c + 1] + soff];
      s1 = *(const float4*)&pack[sbase + koBarr[c + 1] + soff + 8];
    }
    const bf16x8 aS = *(const bf16x8*)&pack[rowSi + koAarr[c] + kb0];
    const bf16x8 aT = *(const bf16x8*)&pack[rowTi + koAarr[c] + kb0];
    const int cb = c & 1;
#pragma unroll
    for (int n = 0; n < 4; ++n) {
      const bf16x8 bS = *(const bf16x8*)&bufB[cb][n * 16 + r15][kb0];
      const bf16x8 bT = *(const bf16x8*)&bufB[cb][64 + n * 16 + r15][kb0];
      if (c < 9) {
        aSS[n] = __builtin_amdgcn_mfma_f32_16x16x32_bf16(aS, bS, aSS[n], 0, 0, 0);
        aTT[n] = __builtin_amdgcn_mfma_f32_16x16x32_bf16(aT, bT, aTT[n], 0, 0, 0);
        aST1[n] = __builtin_amdgcn_mfma_f32_16x16x32_bf16(aS, bT, aST1[n], 0, 0, 0);
        aST2[n] = __builtin_amdgcn_mfma_f32_16x16x32_bf16(aT, bS, aST2[n], 0, 0, 0);
      } else {
        wSS[n] = __builtin_amdgcn_mfma_f32_16x16x32_bf16(aS, bS, wSS[n], 0, 0, 0);
        wTT[n] = __builtin_amdgcn_mfma_f32_16x16x32_bf16(aT, bT, wTT[n], 0, 0, 0);
        wST1[n] = __builtin_amdgcn_mfma_f32_16x16x32_bf16(aS, bT, wST1[n], 0, 0, 0);
        wST2[n] = __builtin_amdgcn_mfma_f32_16x16x32_bf16(aT, bS, wST2[n], 0, 0, 0);
      }
    }
    if (c < 9) {
      const int nb = (c + 1) & 1;
      *(float4*)&bufB[nb][srow][soff] = s0;
      *(float4*)&bufB[nb][srow][soff + 8] = s1;
    }
  }

  // epilogue: l2 = -2*acc per stream, 5-kernel exp, symmetric combine
  const float nc0 = negc[0], nc1 = negc[1], nc2 = negc[2], nc3 = negc[3],
              nc4 = negc[4];
  double tsum = 0.0;
#pragma unroll
  for (int n = 0; n < 4; ++n) {
#pragma unroll
    for (int e = 0; e < 4; ++e) {
      const float l2ss = -2.f * aSS[n][e];
      const float l2tt = -2.f * aTT[n][e];
      const float l2s1 = -2.f * aST1[n][e];
      const float l2s2 = -2.f * aST2[n][e];
      const float Kss = __expf(l2ss * nc0) + __expf(l2ss * nc1) +
                        __expf(l2ss * nc2) + __expf(l2ss * nc3) +
                        __expf(l2ss * nc4);
      const float Ktt = __expf(l2tt * nc0) + __expf(l2tt * nc1) +
                        __expf(l2tt * nc2) + __expf(l2tt * nc3) +
                        __expf(l2tt * nc4);
      const float Ks1 = __expf(l2s1 * nc0) + __expf(l2s1 * nc1) +
                        __expf(l2s1 * nc2) + __expf(l2s1 * nc3) +
                        __expf(l2s1 * nc4);
      const float Ks2 = __expf(l2s2 * nc0) + __expf(l2s2 * nc1) +
                        __expf(l2s2 * nc2) + __expf(l2s2 * nc3) +
                        __expf(l2s2 * nc4);
      tsum += (double)(wSS[n][e] * Kss + wTT[n][e] * Ktt -
                       wST1[n][e] * Ks1 - wST2[n][e] * Ks2);
    }
  }
  if (bi != bj) tsum *= 2.0;
  dred[t] = tsum;
  __syncthreads();
  for (int s = 128; s; s >>= 1) {
    if (t < s) dred[t] += dred[t + s];
    __syncthreads();
  }
  if (t == 0) {
    atomicAdd(accOut, dred[0]);
    __threadfence();
    if (atomicAdd(counter2, 1) == 4095) {
      double v = atomicAdd(accOut, 0.0);
      out[0] = (float)v;
    }
  }
}

extern "C" void kernel_launch(void* const* d_in, const int* in_sizes, int n_in,
                              void* d_out, int out_size, void* d_ws,
                              size_t ws_size, hipStream_t stream) {
  const float* source = (const float*)d_in[0];
  const float* target = (const float*)d_in[1];
  const float* s_label = (const float*)d_in[2];
  const float* t_label = (const float*)d_in[3];

  double* acc = (double*)d_ws;   // [0] loss
  double* sumsq = acc + 1;       // [1]
  double* colsum = acc + 2;      // [2..257]
  double* labsumS = acc + 258;   // [258..289]
  double* labsumT = acc + 290;   // [290..321]
  int* counter1 = (int*)((char*)d_ws + 2576);
  int* counter2 = (int*)((char*)d_ws + 2580);
  float* fbase = (float*)((char*)d_ws + 2624);
  float* aScale = fbase;         // 32
  float* bScale = fbase + 32;    // 32
  float* negc = fbase + 64;      // 8
  unsigned short* pack = (unsigned short*)((char*)d_ws + 4096);  // 8192*352

  hipMemsetAsync(d_ws, 0, 2624, stream);
  stats_kernel<<<256, 256, 0, stream>>>(source, target, s_label, t_label,
                                        colsum, sumsq, labsumS, labsumT,
                                        counter1, negc, aScale, bScale);
  pack_kernel<<<2048, 256, 0, stream>>>(source, target, s_label, t_label,
                                        aScale, bScale, pack);
  lmmd_main<<<4096, 256, 0, stream>>>(pack, negc, acc, counter2,
                                      (float*)d_out);
}